// Round 6
// baseline (142.288 us; speedup 1.0000x reference)
//
#include <hip/hip_runtime.h>
#include <math.h>

#define BB   8
#define CC   256
#define HH   56
#define WW   56
#define KK   3
#define MIDN 51
#define NTAP (KK*KK)          // 9
#define CKK  (CC*NTAP)        // 2304
#define HW   (HH*WW)          // 3136
#define SPIX 64               // pixels per K1 strip
#define NSTR (HW/SPIX)        // 49 strips, exact
#define CPR  128              // channels per K1 round (2 rounds)
#define XSTR 65               // K1 LDS tile stride: bank (c+p)%32, <=2 lanes/bank
#define NCPB 4                // channels per ddf block
#define TROW 68               // K3 tile row stride (17 float4, bank-rotating)
#define TPL  (58*TROW)        // 3944 floats per halo plane

// ============ K1: sf (full channel reduction + norm) + pooled-mean partials ============
// grid: BB*NSTR = 392 blocks, 256 threads. Each block owns 64 pixels and ALL 256
// channels (2 rounds of 128 through LDS). Writes sf directly (normalized).
__global__ __launch_bounds__(256) void k_sf(const float* __restrict__ x,
                                            const float* __restrict__ ws,
                                            const float* __restrict__ bs,
                                            float* __restrict__ sf,
                                            float* __restrict__ poolpart) {
    int blk = blockIdx.x;
    int s = blk % NSTR;
    int b = blk / NSTR;
    int t = threadIdx.x;
    int p = t & 63;           // pixel within strip
    int q = t >> 6;           // channel quarter (32 channels per round)
    __shared__ float xs[CPR * XSTR];          // [128 ch][65] = 33.3 KB
    __shared__ float wss[NTAP][CC];           // 9 KB
    __shared__ float accq[NTAP * 4 * SPIX];   // 9 KB
    for (int idx = t; idx < NTAP * CC; idx += 256)
        ((float*)wss)[idx] = ws[idx];         // ws is (9,256) row-major
    float acc[NTAP];
    #pragma unroll
    for (int n = 0; n < NTAP; ++n) acc[n] = 0.f;
    const float* xb = x + ((size_t)b * CC) * HW + s * SPIX;
    #pragma unroll
    for (int r = 0; r < 2; ++r) {
        if (r) __syncthreads();               // round-0 readers done before restage
        // stage 32 channels per thread: load to regs, then LDS (transposed)
        float vv[32];
        #pragma unroll
        for (int c = 0; c < 32; ++c)
            vv[c] = xb[(size_t)(r * CPR + q * 32 + c) * HW + p];
        #pragma unroll
        for (int c = 0; c < 32; ++c)
            xs[(q * 32 + c) * XSTR + p] = vv[c];
        __syncthreads();
        // pool: per-channel sum over the 64 strip pixels (threads 0..127)
        if (t < CPR) {
            float sum = 0.f;
            #pragma unroll 8
            for (int pp = 0; pp < SPIX; ++pp) sum += xs[t * XSTR + pp];
            poolpart[((size_t)(b * NSTR + s)) * CC + r * CPR + t] = sum;
        }
        // dot: 32 channels x 9 taps per thread
        #pragma unroll 4
        for (int c = 0; c < 32; ++c) {
            float xv = xs[(q * 32 + c) * XSTR + p];
            #pragma unroll
            for (int n = 0; n < NTAP; ++n)
                acc[n] += xv * wss[n][r * CPR + q * 32 + c];
        }
    }
    #pragma unroll
    for (int n = 0; n < NTAP; ++n) accq[(n * 4 + q) * SPIX + p] = acc[n];
    __syncthreads();
    if (t < SPIX) {
        float y[NTAP];
        #pragma unroll
        for (int n = 0; n < NTAP; ++n) {
            float v = bs[n];
            #pragma unroll
            for (int qq = 0; qq < 4; ++qq) v += accq[(n * 4 + qq) * SPIX + t];
            y[n] = v;
        }
        float mean = 0.f;
        #pragma unroll
        for (int n = 0; n < NTAP; ++n) mean += y[n];
        mean *= (1.f / NTAP);
        float var = 0.f;
        #pragma unroll
        for (int n = 0; n < NTAP; ++n) { float d = y[n] - mean; var += d * d; }
        float inv = 0.47140452079103173f /    // GAIN/K = sqrt(2)/3
                    (sqrtf(var * (1.f / (NTAP - 1))) + 1e-10f);
        #pragma unroll
        for (int n = 0; n < NTAP; ++n)
            sf[((size_t)(b * NTAP + n)) * HW + s * SPIX + t] = (y[n] - mean) * inv;
    }
}

// ============ K2: DDF apply with inline MLP — 4px/thread b128 path ============
// grid: BB*CC/NCPB = 512 blocks, 512 threads. __launch_bounds__(512,4) pins
// VGPR<=128 -> guaranteed 2 blocks/CU, 16 waves/CU (the round-1 b128 attempt
// likely lost this and halved occupancy). Tile [58][TROW=68], x col m -> tile
// col m+4; staging and zeroing are aligned b128; compute reads 3x b128 per
// (u,channel) at 16B lane stride (conflict-free); sf/out are float4 coalesced.
__global__ __launch_bounds__(512, 4) void k_ddf(const float* __restrict__ x,
                                                const float* __restrict__ poolpart,
                                                const float* __restrict__ w1,
                                                const float* __restrict__ b1,
                                                const float* __restrict__ w2,
                                                const float* __restrict__ b2,
                                                const float* __restrict__ fn_std,
                                                const float* __restrict__ sf,
                                                float* __restrict__ out) {
    int blk = blockIdx.x;
    int b = blk / (CC / NCPB), cg = blk % (CC / NCPB);
    int c0 = cg * NCPB;
    int t = threadIdx.x;
    __shared__ __align__(16) float xt[NCPB][TPL];   // 63.1 KB
    __shared__ float ps[CC];                  // pooled means
    __shared__ float y1s[64];                 // 51 used
    __shared__ float y2s[NCPB * NTAP];        // 36
    __shared__ float cfs[NCPB * NTAP];        // 36
    {
        float4 z4 = make_float4(0.f, 0.f, 0.f, 0.f);
        float4* xt4 = (float4*)xt;
        for (int i4 = t; i4 < NCPB * TPL / 4; i4 += 512) xt4[i4] = z4;
    }
    __syncthreads();
    // stage 4 contiguous planes: global float4 -> aligned LDS float4
    const float4* xp4 = (const float4*)(x + ((size_t)(b * CC + c0)) * HW);
    for (int i4 = t; i4 < NCPB * HW / 4; i4 += 512) {
        float4 v = xp4[i4];
        int k = i4 / (HW / 4);                 // plane
        int rem4 = i4 - k * (HW / 4);          // float4 index within plane
        int r = rem4 / (WW / 4);               // row
        int col = 4 * (rem4 - r * (WW / 4));   // col (multiple of 4)
        *(float4*)&xt[k][(r + 1) * TROW + col + 4] = v;
    }
    // ---- inline MLP (overlaps with staging latency) ----
    if (t < CC) {
        float s = 0.f;
        const float* pp = poolpart + ((size_t)b * NSTR) * CC + t;
        for (int st = 0; st < NSTR; ++st) s += pp[(size_t)st * CC];
        ps[t] = s * (1.0f / HW);
    }
    __syncthreads();
    if (t < MIDN) {
        float a = b1[t];
        const float* wr = w1 + t * CC;
        for (int c2 = 0; c2 < CC; ++c2) a += ps[c2] * wr[c2];
        y1s[t] = fmaxf(a, 0.f);
    }
    __syncthreads();
    if (t < NCPB * NTAP) {
        int row = c0 * NTAP + t;               // (c0+k)*9+q
        float a = b2[row];
        const float* r = w2 + (size_t)row * MIDN;
        #pragma unroll 3
        for (int m = 0; m < MIDN; ++m) a += y1s[m] * r[m];
        y2s[t] = a;
    }
    __syncthreads();
    if (t < NCPB) {
        float y2[NTAP];
        #pragma unroll
        for (int q = 0; q < NTAP; ++q) y2[q] = y2s[t * NTAP + q];
        float mean = 0.f;
        #pragma unroll
        for (int q = 0; q < NTAP; ++q) mean += y2[q];
        mean *= (1.f / NTAP);
        float var = 0.f;
        #pragma unroll
        for (int q = 0; q < NTAP; ++q) { float d = y2[q] - mean; var += d * d; }
        float inv = 1.f / (sqrtf(var * (1.f / (NTAP - 1))) + 1e-10f);
        #pragma unroll
        for (int q = 0; q < NTAP; ++q)
            cfs[t * NTAP + q] = (y2[q] - mean) * inv * fn_std[(c0 + t) * NTAP + q];
    }
    __syncthreads();
    float cf9[NCPB][NTAP];
    #pragma unroll
    for (int k = 0; k < NCPB; ++k)
        #pragma unroll
        for (int n = 0; n < NTAP; ++n) cf9[k][n] = cfs[k * NTAP + n];
    // ---- ddf apply: 4 outputs/thread, b128 LDS reads, float4 sf/out ----
    const float* sfb = sf + (size_t)b * NTAP * HW;
    float* op = out + ((size_t)(b * CC + c0)) * HW;
    for (int g4 = t; g4 < HW / 4; g4 += 512) {     // 784 groups
        int i = g4 / (WW / 4);
        int j0 = 4 * (g4 - i * (WW / 4));
        int pix = i * WW + j0;
        float acc[NCPB][4];
        #pragma unroll
        for (int k = 0; k < NCPB; ++k) {
            acc[k][0] = 0.f; acc[k][1] = 0.f; acc[k][2] = 0.f; acc[k][3] = 0.f;
        }
        #pragma unroll
        for (int u = 0; u < KK; ++u) {
            float4 s0 = *(const float4*)&sfb[(size_t)(u * 3 + 0) * HW + pix];
            float4 s1 = *(const float4*)&sfb[(size_t)(u * 3 + 1) * HW + pix];
            float4 s2 = *(const float4*)&sfb[(size_t)(u * 3 + 2) * HW + pix];
            int base = (i + u) * TROW + j0;        // tile col j0 = x col j0-4
            #pragma unroll
            for (int k = 0; k < NCPB; ++k) {
                float4 A = *(const float4*)&xt[k][base];        // x j0-4..j0-1
                float4 B = *(const float4*)&xt[k][base + 4];    // x j0  ..j0+3
                float4 C = *(const float4*)&xt[k][base + 8];    // x j0+4..j0+7
                float w0 = A.w, w1 = B.x, w2 = B.y, w3 = B.z, w4 = B.w, w5 = C.x;
                float c_0 = cf9[k][u * 3 + 0];
                float c_1 = cf9[k][u * 3 + 1];
                float c_2 = cf9[k][u * 3 + 2];
                acc[k][0] += w0 * (c_0 * s0.x) + w1 * (c_1 * s1.x) + w2 * (c_2 * s2.x);
                acc[k][1] += w1 * (c_0 * s0.y) + w2 * (c_1 * s1.y) + w3 * (c_2 * s2.y);
                acc[k][2] += w2 * (c_0 * s0.z) + w3 * (c_1 * s1.z) + w4 * (c_2 * s2.z);
                acc[k][3] += w3 * (c_0 * s0.w) + w4 * (c_1 * s1.w) + w5 * (c_2 * s2.w);
            }
        }
        #pragma unroll
        for (int k = 0; k < NCPB; ++k) {
            float4 o4 = make_float4(acc[k][0], acc[k][1], acc[k][2], acc[k][3]);
            *(float4*)&op[(size_t)k * HW + pix] = o4;
        }
    }
}

extern "C" void kernel_launch(void* const* d_in, const int* in_sizes, int n_in,
                              void* d_out, int out_size, void* d_ws, size_t ws_size,
                              hipStream_t stream) {
    const float* x      = (const float*)d_in[0];
    const float* w1     = (const float*)d_in[1];
    const float* b1     = (const float*)d_in[2];
    const float* w2     = (const float*)d_in[3];
    const float* b2     = (const float*)d_in[4];
    const float* ws     = (const float*)d_in[5];
    const float* bs     = (const float*)d_in[6];
    const float* fn_std = (const float*)d_in[7];
    float* out = (float*)d_out;

    float* wsf      = (float*)d_ws;
    float* sf       = wsf;                         // BB*NTAP*HW = 225792
    float* poolpart = sf + 225792;                 // BB*NSTR*CC = 100352

    k_sf<<<BB * NSTR, 256, 0, stream>>>(x, ws, bs, sf, poolpart);
    k_ddf<<<BB * (CC / NCPB), 512, 0, stream>>>(x, poolpart, w1, b1, w2, b2,
                                                fn_std, sf, out);
}

// Round 7
// 114.765 us; speedup vs baseline: 1.2398x; 1.2398x over previous
//
#include <hip/hip_runtime.h>
#include <math.h>

#define BB   8
#define CC   256
#define HH   56
#define WW   56
#define KK   3
#define MIDN 51
#define NTAP (KK*KK)          // 9
#define CKK  (CC*NTAP)        // 2304
#define HW   (HH*WW)          // 3136
#define SPIX 64               // pixels per K1 strip
#define NSTR (HW/SPIX)        // 49 strips, exact
#define CPR  128              // channels per K1 round (2 rounds)
#define XSTR 65               // K1 LDS tile stride: bank (c+p)%32, <=2 lanes/bank
#define NCPB 4                // channels per ddf block
#define TILE 3364             // 58*58 halo tile

// ============ K1: sf (full channel reduction + norm) + pooled-mean partials ============
// grid: BB*NSTR = 392 blocks, 256 threads. Each block owns 64 pixels and ALL 256
// channels (2 rounds of 128 through LDS). Writes sf directly (normalized).
__global__ __launch_bounds__(256) void k_sf(const float* __restrict__ x,
                                            const float* __restrict__ ws,
                                            const float* __restrict__ bs,
                                            float* __restrict__ sf,
                                            float* __restrict__ poolpart) {
    int blk = blockIdx.x;
    int s = blk % NSTR;
    int b = blk / NSTR;
    int t = threadIdx.x;
    int p = t & 63;           // pixel within strip
    int q = t >> 6;           // channel quarter (32 channels per round)
    __shared__ float xs[CPR * XSTR];          // [128 ch][65] = 33.3 KB
    __shared__ float wss[NTAP][CC];           // 9 KB
    __shared__ float accq[NTAP * 4 * SPIX];   // 9 KB
    for (int idx = t; idx < NTAP * CC; idx += 256)
        ((float*)wss)[idx] = ws[idx];         // ws is (9,256) row-major
    float acc[NTAP];
    #pragma unroll
    for (int n = 0; n < NTAP; ++n) acc[n] = 0.f;
    const float* xb = x + ((size_t)b * CC) * HW + s * SPIX;
    #pragma unroll
    for (int r = 0; r < 2; ++r) {
        if (r) __syncthreads();               // round-0 readers done before restage
        // stage 32 channels per thread: load to regs, then LDS (transposed)
        float vv[32];
        #pragma unroll
        for (int c = 0; c < 32; ++c)
            vv[c] = xb[(size_t)(r * CPR + q * 32 + c) * HW + p];
        #pragma unroll
        for (int c = 0; c < 32; ++c)
            xs[(q * 32 + c) * XSTR + p] = vv[c];
        __syncthreads();
        // pool: per-channel sum over the 64 strip pixels (threads 0..127)
        if (t < CPR) {
            float sum = 0.f;
            #pragma unroll 8
            for (int pp = 0; pp < SPIX; ++pp) sum += xs[t * XSTR + pp];
            poolpart[((size_t)(b * NSTR + s)) * CC + r * CPR + t] = sum;
        }
        // dot: 32 channels x 9 taps per thread
        #pragma unroll 4
        for (int c = 0; c < 32; ++c) {
            float xv = xs[(q * 32 + c) * XSTR + p];
            #pragma unroll
            for (int n = 0; n < NTAP; ++n)
                acc[n] += xv * wss[n][r * CPR + q * 32 + c];
        }
    }
    #pragma unroll
    for (int n = 0; n < NTAP; ++n) accq[(n * 4 + q) * SPIX + p] = acc[n];
    __syncthreads();
    if (t < SPIX) {
        float y[NTAP];
        #pragma unroll
        for (int n = 0; n < NTAP; ++n) {
            float v = bs[n];
            #pragma unroll
            for (int qq = 0; qq < 4; ++qq) v += accq[(n * 4 + qq) * SPIX + t];
            y[n] = v;
        }
        float mean = 0.f;
        #pragma unroll
        for (int n = 0; n < NTAP; ++n) mean += y[n];
        mean *= (1.f / NTAP);
        float var = 0.f;
        #pragma unroll
        for (int n = 0; n < NTAP; ++n) { float d = y[n] - mean; var += d * d; }
        float inv = 0.47140452079103173f /    // GAIN/K = sqrt(2)/3
                    (sqrtf(var * (1.f / (NTAP - 1))) + 1e-10f);
        #pragma unroll
        for (int n = 0; n < NTAP; ++n)
            sf[((size_t)(b * NTAP + n)) * HW + s * SPIX + t] = (y[n] - mean) * inv;
    }
}

// ============ K2: DDF apply with inline MLP (proven scalar form) ============
// grid: BB*CC/NCPB = 512 blocks, 512 threads. Per block: recompute the batch's
// tiny MLP for its own 4 channels (pooled reduce -> y1 -> y2 -> norm -> cf in
// LDS), overlapped with x halo-tile staging; then the scalar ddf loop.
// Scalar per-pixel mapping is the verified optimum: register-lean (no spills,
// vs r6's VGPR=64 + 58MB scratch traffic), perfectly coalesced out stores,
// <=2 lanes/bank scalar LDS reads (r6's b128 had 4.28M conflict cycles).
// LDS 53.8 + 1.6 KB -> 2 blocks/CU, 16 waves/CU.
__global__ __launch_bounds__(512) void k_ddf(const float* __restrict__ x,
                                             const float* __restrict__ poolpart,
                                             const float* __restrict__ w1,
                                             const float* __restrict__ b1,
                                             const float* __restrict__ w2,
                                             const float* __restrict__ b2,
                                             const float* __restrict__ fn_std,
                                             const float* __restrict__ sf,
                                             float* __restrict__ out) {
    int blk = blockIdx.x;
    int b = blk / (CC / NCPB), cg = blk % (CC / NCPB);
    int c0 = cg * NCPB;
    int t = threadIdx.x;
    __shared__ float xt[NCPB][TILE];          // 53.8 KB
    __shared__ float ps[CC];                  // pooled means
    __shared__ float y1s[64];                 // 51 used
    __shared__ float y2s[NCPB * NTAP];        // 36
    __shared__ float cfs[NCPB * NTAP];        // 36
    for (int idx = t; idx < NCPB * TILE; idx += 512) ((float*)xt)[idx] = 0.f;
    __syncthreads();
    // stage 4 contiguous planes with float4 loads (NCPB*HW/4 = 3136 float4s)
    const float4* xp4 = (const float4*)(x + ((size_t)(b * CC + c0)) * HW);
    for (int i4 = t; i4 < NCPB * HW / 4; i4 += 512) {
        float4 v = xp4[i4];
        int k = i4 / (HW / 4);                 // plane
        int rem4 = i4 - k * (HW / 4);          // float4 index within plane
        int r = rem4 / (WW / 4);               // row
        int col = 4 * (rem4 - r * (WW / 4));   // col (multiple of 4)
        float* d = &xt[k][(r + 1) * 58 + col + 1];
        d[0] = v.x; d[1] = v.y; d[2] = v.z; d[3] = v.w;
    }
    // ---- inline MLP (overlaps with staging latency) ----
    if (t < CC) {
        float s = 0.f;
        const float* pp = poolpart + ((size_t)b * NSTR) * CC + t;
        for (int st = 0; st < NSTR; ++st) s += pp[(size_t)st * CC];
        ps[t] = s * (1.0f / HW);
    }
    __syncthreads();
    if (t < MIDN) {
        float a = b1[t];
        const float* wr = w1 + t * CC;
        for (int c2 = 0; c2 < CC; ++c2) a += ps[c2] * wr[c2];
        y1s[t] = fmaxf(a, 0.f);
    }
    __syncthreads();
    if (t < NCPB * NTAP) {
        int row = c0 * NTAP + t;               // (c0+k)*9+q
        float a = b2[row];
        const float* r = w2 + (size_t)row * MIDN;
        #pragma unroll 3
        for (int m = 0; m < MIDN; ++m) a += y1s[m] * r[m];
        y2s[t] = a;
    }
    __syncthreads();
    if (t < NCPB) {
        float y2[NTAP];
        #pragma unroll
        for (int q = 0; q < NTAP; ++q) y2[q] = y2s[t * NTAP + q];
        float mean = 0.f;
        #pragma unroll
        for (int q = 0; q < NTAP; ++q) mean += y2[q];
        mean *= (1.f / NTAP);
        float var = 0.f;
        #pragma unroll
        for (int q = 0; q < NTAP; ++q) { float d = y2[q] - mean; var += d * d; }
        float inv = 1.f / (sqrtf(var * (1.f / (NTAP - 1))) + 1e-10f);
        #pragma unroll
        for (int q = 0; q < NTAP; ++q)
            cfs[t * NTAP + q] = (y2[q] - mean) * inv * fn_std[(c0 + t) * NTAP + q];
    }
    __syncthreads();
    float cf9[NCPB][NTAP];
    #pragma unroll
    for (int k = 0; k < NCPB; ++k)
        #pragma unroll
        for (int n = 0; n < NTAP; ++n) cf9[k][n] = cfs[k * NTAP + n];
    // ---- ddf apply (scalar form, coalesced per-pixel mapping) ----
    const float* sfb = sf + (size_t)b * NTAP * HW;
    float* op = out + ((size_t)(b * CC + c0)) * HW;
    for (int idx = t; idx < HW; idx += 512) {
        int i = idx / WW, j = idx - i * WW;
        float s9[NTAP];
        #pragma unroll
        for (int n = 0; n < NTAP; ++n) s9[n] = sfb[(size_t)n * HW + idx];
        float acc[NCPB];
        #pragma unroll
        for (int k = 0; k < NCPB; ++k) acc[k] = 0.f;
        #pragma unroll
        for (int u = 0; u < KK; ++u)
            #pragma unroll
            for (int v = 0; v < KK; ++v) {
                int n = u * KK + v;
                int o = (i + u) * 58 + (j + v);
                #pragma unroll
                for (int k = 0; k < NCPB; ++k)
                    acc[k] += xt[k][o] * (cf9[k][n] * s9[n]);
            }
        #pragma unroll
        for (int k = 0; k < NCPB; ++k) op[(size_t)k * HW + idx] = acc[k];
    }
}

extern "C" void kernel_launch(void* const* d_in, const int* in_sizes, int n_in,
                              void* d_out, int out_size, void* d_ws, size_t ws_size,
                              hipStream_t stream) {
    const float* x      = (const float*)d_in[0];
    const float* w1     = (const float*)d_in[1];
    const float* b1     = (const float*)d_in[2];
    const float* w2     = (const float*)d_in[3];
    const float* b2     = (const float*)d_in[4];
    const float* ws     = (const float*)d_in[5];
    const float* bs     = (const float*)d_in[6];
    const float* fn_std = (const float*)d_in[7];
    float* out = (float*)d_out;

    float* wsf      = (float*)d_ws;
    float* sf       = wsf;                         // BB*NTAP*HW = 225792
    float* poolpart = sf + 225792;                 // BB*NSTR*CC = 100352

    k_sf<<<BB * NSTR, 256, 0, stream>>>(x, ws, bs, sf, poolpart);
    k_ddf<<<BB * (CC / NCPB), 512, 0, stream>>>(x, poolpart, w1, b1, w2, b2,
                                                fn_std, sf, out);
}

// Round 8
// 113.873 us; speedup vs baseline: 1.2495x; 1.0078x over previous
//
#include <hip/hip_runtime.h>
#include <math.h>

#define BB   8
#define CC   256
#define HH   56
#define WW   56
#define KK   3
#define MIDN 51
#define NTAP (KK*KK)          // 9
#define CKK  (CC*NTAP)        // 2304
#define HW   (HH*WW)          // 3136
#define SPIX 64               // pixels per K1 strip
#define NSTR (HW/SPIX)        // 49 strips, exact
#define CPR  128              // channels per K1 round (2 rounds)
#define XSTR 65               // K1 LDS tile stride: bank (c+p)%32, <=2 lanes/bank
#define NCPB 4                // channels per ddf block
#define TILE 3364             // 58*58 halo tile

// ============ K1: sf (full channel reduction + norm) + pooled-mean partials ============
// grid: BB*NSTR = 392 blocks, 256 threads. Each block owns 64 pixels and ALL 256
// channels (2 rounds of 128 through LDS). Writes sf directly (normalized).
__global__ __launch_bounds__(256) void k_sf(const float* __restrict__ x,
                                            const float* __restrict__ ws,
                                            const float* __restrict__ bs,
                                            float* __restrict__ sf,
                                            float* __restrict__ poolpart) {
    int blk = blockIdx.x;
    int s = blk % NSTR;
    int b = blk / NSTR;
    int t = threadIdx.x;
    int p = t & 63;           // pixel within strip
    int q = t >> 6;           // channel quarter (32 channels per round)
    __shared__ float xs[CPR * XSTR];          // [128 ch][65] = 33.3 KB
    __shared__ float wss[NTAP][CC];           // 9 KB
    __shared__ float accq[NTAP * 4 * SPIX];   // 9 KB
    for (int idx = t; idx < NTAP * CC; idx += 256)
        ((float*)wss)[idx] = ws[idx];         // ws is (9,256) row-major
    float acc[NTAP];
    #pragma unroll
    for (int n = 0; n < NTAP; ++n) acc[n] = 0.f;
    const float* xb = x + ((size_t)b * CC) * HW + s * SPIX;
    #pragma unroll
    for (int r = 0; r < 2; ++r) {
        if (r) __syncthreads();               // round-0 readers done before restage
        // stage 32 channels per thread: load to regs, then LDS (transposed)
        float vv[32];
        #pragma unroll
        for (int c = 0; c < 32; ++c)
            vv[c] = xb[(size_t)(r * CPR + q * 32 + c) * HW + p];
        #pragma unroll
        for (int c = 0; c < 32; ++c)
            xs[(q * 32 + c) * XSTR + p] = vv[c];
        __syncthreads();
        // pool: per-channel sum over the 64 strip pixels (threads 0..127)
        if (t < CPR) {
            float sum = 0.f;
            #pragma unroll 8
            for (int pp = 0; pp < SPIX; ++pp) sum += xs[t * XSTR + pp];
            poolpart[((size_t)(b * NSTR + s)) * CC + r * CPR + t] = sum;
        }
        // dot: 32 channels x 9 taps per thread
        #pragma unroll 4
        for (int c = 0; c < 32; ++c) {
            float xv = xs[(q * 32 + c) * XSTR + p];
            #pragma unroll
            for (int n = 0; n < NTAP; ++n)
                acc[n] += xv * wss[n][r * CPR + q * 32 + c];
        }
    }
    #pragma unroll
    for (int n = 0; n < NTAP; ++n) accq[(n * 4 + q) * SPIX + p] = acc[n];
    __syncthreads();
    if (t < SPIX) {
        float y[NTAP];
        #pragma unroll
        for (int n = 0; n < NTAP; ++n) {
            float v = bs[n];
            #pragma unroll
            for (int qq = 0; qq < 4; ++qq) v += accq[(n * 4 + qq) * SPIX + t];
            y[n] = v;
        }
        float mean = 0.f;
        #pragma unroll
        for (int n = 0; n < NTAP; ++n) mean += y[n];
        mean *= (1.f / NTAP);
        float var = 0.f;
        #pragma unroll
        for (int n = 0; n < NTAP; ++n) { float d = y[n] - mean; var += d * d; }
        float inv = 0.47140452079103173f /    // GAIN/K = sqrt(2)/3
                    (sqrtf(var * (1.f / (NTAP - 1))) + 1e-10f);
        #pragma unroll
        for (int n = 0; n < NTAP; ++n)
            sf[((size_t)(b * NTAP + n)) * HW + s * SPIX + t] = (y[n] - mean) * inv;
    }
}

// ============ K2: DDF apply, inline MLP, column-sliding register window ============
// grid: BB*CC/NCPB = 512 blocks, 448 threads (7 waves). Thread t owns column
// j=t%56, rows oct*7..oct*7+6 (oct=t/56). 3x3x4ch input window in registers:
// slide down = 12 new LDS reads/pixel (vs 36 scalar) with the SAME stride-1
// bank pattern (2 lanes/bank, free), coalesced sf loads + out stores (56-wide
// runs), ~95 VGPR (no spill; cap 170 via __launch_bounds__(448,3)).
// LDS 55.4 KB -> 2 blocks/CU, 14 waves/CU. Staging: 3136/448 = 7 exact.
__global__ __launch_bounds__(448, 3) void k_ddf(const float* __restrict__ x,
                                                const float* __restrict__ poolpart,
                                                const float* __restrict__ w1,
                                                const float* __restrict__ b1,
                                                const float* __restrict__ w2,
                                                const float* __restrict__ b2,
                                                const float* __restrict__ fn_std,
                                                const float* __restrict__ sf,
                                                float* __restrict__ out) {
    int blk = blockIdx.x;
    int b = blk / (CC / NCPB), cg = blk % (CC / NCPB);
    int c0 = cg * NCPB;
    int t = threadIdx.x;
    __shared__ float xt[NCPB][TILE];          // 53.8 KB
    __shared__ float ps[CC];                  // pooled means
    __shared__ float y1s[64];                 // 51 used
    __shared__ float y2s[NCPB * NTAP];        // 36
    __shared__ float cfs[NCPB * NTAP];        // 36
    for (int idx = t; idx < NCPB * TILE; idx += 448) ((float*)xt)[idx] = 0.f;
    __syncthreads();
    // stage 4 contiguous planes with float4 loads (3136 float4s = 7/thread)
    const float4* xp4 = (const float4*)(x + ((size_t)(b * CC + c0)) * HW);
    for (int i4 = t; i4 < NCPB * HW / 4; i4 += 448) {
        float4 v = xp4[i4];
        int k = i4 / (HW / 4);                 // plane
        int rem4 = i4 - k * (HW / 4);          // float4 index within plane
        int r = rem4 / (WW / 4);               // row
        int col = 4 * (rem4 - r * (WW / 4));   // col (multiple of 4)
        float* d = &xt[k][(r + 1) * 58 + col + 1];
        d[0] = v.x; d[1] = v.y; d[2] = v.z; d[3] = v.w;
    }
    // ---- inline MLP (overlaps with staging latency) ----
    if (t < CC) {
        float s = 0.f;
        const float* pp = poolpart + ((size_t)b * NSTR) * CC + t;
        for (int st = 0; st < NSTR; ++st) s += pp[(size_t)st * CC];
        ps[t] = s * (1.0f / HW);
    }
    __syncthreads();
    if (t < MIDN) {
        float a = b1[t];
        const float* wr = w1 + t * CC;
        for (int c2 = 0; c2 < CC; ++c2) a += ps[c2] * wr[c2];
        y1s[t] = fmaxf(a, 0.f);
    }
    __syncthreads();
    if (t < NCPB * NTAP) {
        int row = c0 * NTAP + t;               // (c0+k)*9+q
        float a = b2[row];
        const float* r = w2 + (size_t)row * MIDN;
        #pragma unroll 3
        for (int m = 0; m < MIDN; ++m) a += y1s[m] * r[m];
        y2s[t] = a;
    }
    __syncthreads();
    if (t < NCPB) {
        float y2[NTAP];
        #pragma unroll
        for (int q = 0; q < NTAP; ++q) y2[q] = y2s[t * NTAP + q];
        float mean = 0.f;
        #pragma unroll
        for (int q = 0; q < NTAP; ++q) mean += y2[q];
        mean *= (1.f / NTAP);
        float var = 0.f;
        #pragma unroll
        for (int q = 0; q < NTAP; ++q) { float d = y2[q] - mean; var += d * d; }
        float inv = 1.f / (sqrtf(var * (1.f / (NTAP - 1))) + 1e-10f);
        #pragma unroll
        for (int q = 0; q < NTAP; ++q)
            cfs[t * NTAP + q] = (y2[q] - mean) * inv * fn_std[(c0 + t) * NTAP + q];
    }
    __syncthreads();
    float cf9[NCPB][NTAP];
    #pragma unroll
    for (int k = 0; k < NCPB; ++k)
        #pragma unroll
        for (int n = 0; n < NTAP; ++n) cf9[k][n] = cfs[k * NTAP + n];
    // ---- ddf apply: column-sliding window ----
    int j = t % WW;            // column 0..55
    int oct = t / WW;          // 0..7
    int i0 = oct * 7;          // first output row
    const float* sfb = sf + (size_t)b * NTAP * HW + j;
    float* op = out + ((size_t)(b * CC + c0)) * HW + j;
    // window regs: wr0/wr1/wr2 = tile rows i, i+1, i+2; cols j..j+2 per channel
    float wr0[NCPB][3], wr1[NCPB][3], wr2[NCPB][3];
    #pragma unroll
    for (int k = 0; k < NCPB; ++k)
        #pragma unroll
        for (int c = 0; c < 3; ++c) {
            wr0[k][c] = xt[k][(i0    ) * 58 + j + c];
            wr1[k][c] = xt[k][(i0 + 1) * 58 + j + c];
        }
    #pragma unroll
    for (int s = 0; s < 7; ++s) {
        int i = i0 + s;
        // load new bottom row (tile row i+2)
        #pragma unroll
        for (int k = 0; k < NCPB; ++k)
            #pragma unroll
            for (int c = 0; c < 3; ++c)
                wr2[k][c] = xt[k][(i + 2) * 58 + j + c];
        // sf taps for this pixel (coalesced: consecutive lanes -> consecutive j)
        float s9[NTAP];
        #pragma unroll
        for (int n = 0; n < NTAP; ++n) s9[n] = sfb[(size_t)n * HW + i * WW];
        #pragma unroll
        for (int k = 0; k < NCPB; ++k) {
            float a = 0.f;
            #pragma unroll
            for (int c = 0; c < 3; ++c) {
                a += wr0[k][c] * (cf9[k][0 * 3 + c] * s9[0 * 3 + c]);
                a += wr1[k][c] * (cf9[k][1 * 3 + c] * s9[1 * 3 + c]);
                a += wr2[k][c] * (cf9[k][2 * 3 + c] * s9[2 * 3 + c]);
            }
            op[(size_t)k * HW + i * WW] = a;
        }
        // rotate window down
        #pragma unroll
        for (int k = 0; k < NCPB; ++k)
            #pragma unroll
            for (int c = 0; c < 3; ++c) {
                wr0[k][c] = wr1[k][c];
                wr1[k][c] = wr2[k][c];
            }
    }
}

extern "C" void kernel_launch(void* const* d_in, const int* in_sizes, int n_in,
                              void* d_out, int out_size, void* d_ws, size_t ws_size,
                              hipStream_t stream) {
    const float* x      = (const float*)d_in[0];
    const float* w1     = (const float*)d_in[1];
    const float* b1     = (const float*)d_in[2];
    const float* w2     = (const float*)d_in[3];
    const float* b2     = (const float*)d_in[4];
    const float* ws     = (const float*)d_in[5];
    const float* bs     = (const float*)d_in[6];
    const float* fn_std = (const float*)d_in[7];
    float* out = (float*)d_out;

    float* wsf      = (float*)d_ws;
    float* sf       = wsf;                         // BB*NTAP*HW = 225792
    float* poolpart = sf + 225792;                 // BB*NSTR*CC = 100352

    k_sf<<<BB * NSTR, 256, 0, stream>>>(x, ws, bs, sf, poolpart);
    k_ddf<<<BB * (CC / NCPB), 448, 0, stream>>>(x, poolpart, w1, b1, w2, b2,
                                                fn_std, sf, out);
}